// Round 2
// baseline (524.047 us; speedup 1.0000x reference)
//
#include <hip/hip_runtime.h>

// Problem constants: B=16, S=512, T=16, P=4, G=S/P=128
#define SDIM 512
#define GDIM 128
#define TDIM 16

// K1: per-patch CAM channel 0 + min/max normalize over t.
// Thread = (patch n, channel-quad q): accumulates float4 over channels 4q..4q+3.
// Wave = 16 patches x 4 quads: each inp load instruction moves 16B/lane = 1KB/wave.
__global__ __launch_bounds__(256) void cam_patch_kernel(const float* __restrict__ inp,
                                                        const float* __restrict__ w3,
                                                        float* __restrict__ top) {
    int gt = blockIdx.x * 256 + threadIdx.x;
    int n  = gt >> 2;        // patch id 0..262143
    int q  = gt & 3;         // channel quad
    int b  = n >> 14;
    int gi = (n >> 7) & 127;
    int gj = n & 127;

    int row0 = b * SDIM + gi * 4;
    int col0 = gj * 4;
    const float* wp = w3 + (size_t)n * 96;   // channel-0 column at k*6

    float4 v = make_float4(0.f, 0.f, 0.f, 0.f);
#pragma unroll
    for (int r = 0; r < 4; ++r) {
        const float4* rp = (const float4*)(inp + ((size_t)(row0 + r) * SDIM + col0) * TDIM) + q;
#pragma unroll
        for (int c = 0; c < 4; ++c) {
            float4 x = rp[c * 4];            // 16 floats per pixel = 4 float4s
            float wk = wp[(r * 4 + c) * 6];  // same addr for 4 lanes -> L1 broadcast
            v.x = fmaf(x.x, wk, v.x);
            v.y = fmaf(x.y, wk, v.y);
            v.z = fmaf(x.z, wk, v.z);
            v.w = fmaf(x.w, wk, v.w);
        }
    }

    // min/max over 16 channels: 4 in-thread + butterfly across the 4-lane group
    float mn = fminf(fminf(v.x, v.y), fminf(v.z, v.w));
    float mx = fmaxf(fmaxf(v.x, v.y), fmaxf(v.z, v.w));
    mn = fminf(mn, __shfl_xor(mn, 1));
    mx = fmaxf(mx, __shfl_xor(mx, 1));
    mn = fminf(mn, __shfl_xor(mn, 2));
    mx = fmaxf(mx, __shfl_xor(mx, 2));

    float inv = 1.0f / (mx - mn);
    float4 o;
    o.x = (v.x - mn) * inv;
    o.y = (v.y - mn) * inv;
    o.z = (v.z - mn) * inv;
    o.w = (v.w - mn) * inv;
    ((float4*)top)[(size_t)n * 4 + q] = o;   // (b,gi,gj,t) layout, contiguous wave store
}

// K2: bilinear upsample (G,G)->(S,S), align_corners=True. One block per output row
// (b,o); stages the two source rows (16 KB contiguous) into LDS; float4 in/out.
__global__ __launch_bounds__(256) void upsample_kernel(const float* __restrict__ top,
                                                       float* __restrict__ out) {
    __shared__ float4 lds[2 * GDIM * 4];     // 2 rows x 128 j x 16 ch = 16 KB

    int b = blockIdx.x >> 9;
    int o = blockIdx.x & 511;

    const float scale = 127.0f / 511.0f;
    float ci = (float)o * scale;
    int i0 = (int)ci; if (i0 > GDIM - 2) i0 = GDIM - 2;
    float wi = ci - (float)i0;

    const float4* src = (const float4*)(top + (size_t)(b * GDIM + i0) * GDIM * TDIM);
#pragma unroll
    for (int idx = threadIdx.x; idx < 2 * GDIM * 4; idx += 256)
        lds[idx] = src[idx];
    __syncthreads();

    float4* ob = (float4*)(out + (size_t)(b * SDIM + o) * SDIM * TDIM);
#pragma unroll
    for (int m = 0; m < 8; ++m) {
        int idx4 = m * 256 + threadIdx.x;    // 0..2047 float4s in this row
        int p = idx4 >> 2;                   // output col 0..511
        int u = idx4 & 3;                    // channel quad
        float cj = (float)p * scale;
        int j0 = (int)cj; if (j0 > GDIM - 2) j0 = GDIM - 2;
        float wj = cj - (float)j0;

        float4 a = lds[j0 * 4 + u];
        float4 bb = lds[j0 * 4 + 4 + u];
        float4 c = lds[GDIM * 4 + j0 * 4 + u];
        float4 d = lds[GDIM * 4 + j0 * 4 + 4 + u];

        float4 r0, r1, res;
        r0.x = a.x + wj * (bb.x - a.x);  r0.y = a.y + wj * (bb.y - a.y);
        r0.z = a.z + wj * (bb.z - a.z);  r0.w = a.w + wj * (bb.w - a.w);
        r1.x = c.x + wj * (d.x - c.x);   r1.y = c.y + wj * (d.y - c.y);
        r1.z = c.z + wj * (d.z - c.z);   r1.w = c.w + wj * (d.w - c.w);
        res.x = r0.x + wi * (r1.x - r0.x);  res.y = r0.y + wi * (r1.y - r0.y);
        res.z = r0.z + wi * (r1.z - r0.z);  res.w = r0.w + wi * (r1.w - r0.w);
        ob[idx4] = res;
    }
}

extern "C" void kernel_launch(void* const* d_in, const int* in_sizes, int n_in,
                              void* d_out, int out_size, void* d_ws, size_t ws_size,
                              hipStream_t stream) {
    const float* inp = (const float*)d_in[0];   // (16,512,512,16) fp32
    const float* w3  = (const float*)d_in[1];   // (262144,16,6) fp32
    float* out = (float*)d_out;                 // (16*512*512,16) fp32
    float* top = (float*)d_ws;                  // (16,128,128,16) fp32 = 16 MB

    // K1: 262144 patches x 4 threads / 256 = 4096 blocks
    cam_patch_kernel<<<4096, 256, 0, stream>>>(inp, w3, top);
    // K2: one block per (b,o) output row = 8192 blocks
    upsample_kernel<<<8192, 256, 0, stream>>>(top, out);
}